// Round 4
// baseline (384.071 us; speedup 1.0000x reference)
//
#include <hip/hip_runtime.h>
#include <math.h>

// x: (32,512,2049) fp32 -> out (32,512,1024) fp32
// segments: n_lin (~631) linear, n_cub (~104) cubic, n_tri (~289) tri-max
#define NI 2049
#define R 4               // rows per thread
#define WCAP 4096
#define NTRI_MAX 512

// ---------------------------------------------------------------------------
// Pass 1: per tri row, find finite-weight window [start, start+cnt).
// ---------------------------------------------------------------------------
__global__ void logscale_win(const float* __restrict__ w, int n_in,
                             int* __restrict__ tri_start,
                             int* __restrict__ tri_cnt) {
    const int i = blockIdx.x;
    __shared__ int smin, smax;
    if (threadIdx.x == 0) { smin = n_in; smax = -1; }
    __syncthreads();
    int lmin = n_in, lmax = -1;
    const float* wr = w + (size_t)i * n_in;
    for (int b = threadIdx.x; b < n_in; b += blockDim.x) {
        float v = wr[b];
        if (v > -1e30f) { lmin = min(lmin, b); lmax = max(lmax, b); }
    }
    atomicMin(&smin, lmin);
    atomicMax(&smax, lmax);
    __syncthreads();
    if (threadIdx.x == 0) {
        int s = smin, cnt = smax - smin + 1;
        if (cnt < 1) { s = 0; cnt = 1; }
        if (cnt > 64) cnt = 64;          // defensive (real max ~28)
        tri_start[i] = s; tri_cnt[i] = cnt;
    }
}

// ---------------------------------------------------------------------------
// Pass 2 (single block): prefix-sum tri counts, build fused meta[n_out],
// compact-pack tri weights.
// meta per output o:
//   lin : x=i0 y=i1 z=f
//   cub : x=i0      z=f
//   tri : x=start y=cnt z=off
// ---------------------------------------------------------------------------
__global__ void logscale_pack(const float* __restrict__ w,
                              const float* __restrict__ flin,
                              const float* __restrict__ fcub,
                              const int*   __restrict__ pidx,
                              const int*   __restrict__ tri_start,
                              const int*   __restrict__ tri_cnt,
                              float4* __restrict__ meta,
                              float*  __restrict__ wpk,
                              int n_lin, int n_cub, int n_tri) {
    __shared__ int offs[NTRI_MAX + 1];
    __shared__ int starts[NTRI_MAX];
    const int tid = threadIdx.x;
    for (int i = tid; i < n_tri; i += blockDim.x) {
        offs[i + 1] = tri_cnt[i];
        starts[i]   = tri_start[i];
    }
    __syncthreads();
    if (tid == 0) {
        offs[0] = 0;
        for (int i = 1; i <= n_tri; ++i) offs[i] += offs[i - 1];
    }
    __syncthreads();
    int total = offs[n_tri]; if (total > WCAP) total = WCAP;

    const int n_out = n_lin + n_cub + n_tri;
    for (int o = tid; o < n_out; o += blockDim.x) {
        float4 m;
        if (o < n_lin) {
            m.x = __int_as_float(pidx[o]);
            m.y = __int_as_float(pidx[n_lin + o]);
            m.z = flin[o]; m.w = 0.0f;
        } else if (o < n_lin + n_cub) {
            float c = fcub[o - n_lin];
            int i0 = (int)floorf(c);
            m.x = __int_as_float(i0);
            m.y = 0.0f;
            m.z = c - (float)i0; m.w = 0.0f;
        } else {
            int i = o - n_lin - n_cub;
            int oa = min(offs[i], WCAP), ob = min(offs[i + 1], WCAP);
            m.x = __int_as_float(starts[i]);
            m.y = __int_as_float(ob - oa);
            m.z = __int_as_float(oa); m.w = 0.0f;
        }
        meta[o] = m;
    }
    for (int p = tid; p < total; p += blockDim.x) {
        int lo = 0, hi = n_tri - 1;
        while (lo < hi) {
            int mid = (lo + hi + 1) >> 1;
            if (offs[mid] <= p) lo = mid; else hi = mid - 1;
        }
        int j = p - offs[lo];
        wpk[p] = w[(size_t)lo * NI + starts[lo] + j];
    }
}

// ---------------------------------------------------------------------------
// Main: pure streaming, no LDS, no barriers. One output x R rows per thread.
// x gathers are near-coalesced (adjacent outputs' indices differ by 1..28)
// and L1/L2/L3-resident; meta (16KB) and wpk (15KB) are L2-resident.
// ---------------------------------------------------------------------------
__global__ __launch_bounds__(256) void logscale_main(
    const float*  __restrict__ x,
    const float4* __restrict__ meta,
    const float*  __restrict__ wpk,
    float* __restrict__ out,
    int n_lin, int n_cub, int n_out, int n_rows, int chunks) {

    const int rg = blockIdx.x / chunks;
    const int ch = blockIdx.x - rg * chunks;
    const int o  = ch * 256 + threadIdx.x;
    if (o >= n_out) return;

    const int row0 = rg * R;
    const int rows_here = min(R, n_rows - row0);

    const float4 m = meta[o];
    const float* xb = x + (size_t)row0 * NI;
    float* ob = out + (size_t)row0 * n_out + o;

    const int n_lc = n_lin + n_cub;

    if (o < n_lin) {
        const int i0 = __float_as_int(m.x);
        const int i1 = __float_as_int(m.y);
        const float f = m.z;
        for (int r = 0; r < rows_here; ++r) {
            const float* xr = xb + (size_t)r * NI;
            const float x0 = xr[i0];
            const float x1 = xr[i1];
            __builtin_nontemporal_store(x0 + f * (x1 - x0), ob + (size_t)r * n_out);
        }
    } else if (o < n_lc) {
        const int i0 = __float_as_int(m.x);
        const float f = m.z;
        for (int r = 0; r < rows_here; ++r) {
            const float* xr = xb + (size_t)r * NI + i0;
            const float xm1 = xr[-1];
            const float x0  = xr[0];
            const float x1  = xr[1];
            const float x2  = xr[2];
            const float res = x0 + 0.5f * f * (x1 - xm1 +
                    f * (2.0f * xm1 - 5.0f * x0 + 4.0f * x1 - x2 +
                    f * (3.0f * (x0 - x1) + x2 - xm1)));
            __builtin_nontemporal_store(res, ob + (size_t)r * n_out);
        }
    } else {
        const int s   = __float_as_int(m.x);
        const int cnt = __float_as_int(m.y);
        const int off = __float_as_int(m.z);
        const float* wp = wpk + off;
        const float* xs = xb + s;
        if (rows_here == R) {
            float a0 = -INFINITY, a1 = -INFINITY, a2 = -INFINITY, a3 = -INFINITY;
            #pragma unroll 4
            for (int j = 0; j < cnt; ++j) {
                const float wj = wp[j];
                a0 = fmaxf(a0, xs[j] + wj);
                a1 = fmaxf(a1, xs[j + NI] + wj);
                a2 = fmaxf(a2, xs[j + 2 * NI] + wj);
                a3 = fmaxf(a3, xs[j + 3 * NI] + wj);
            }
            __builtin_nontemporal_store(a0, ob);
            __builtin_nontemporal_store(a1, ob + n_out);
            __builtin_nontemporal_store(a2, ob + 2 * (size_t)n_out);
            __builtin_nontemporal_store(a3, ob + 3 * (size_t)n_out);
        } else {
            for (int r = 0; r < rows_here; ++r) {
                const float* xr = xs + (size_t)r * NI;
                float mx = -INFINITY;
                for (int j = 0; j < cnt; ++j)
                    mx = fmaxf(mx, xr[j] + wp[j]);
                __builtin_nontemporal_store(mx, ob + (size_t)r * n_out);
            }
        }
    }
}

extern "C" void kernel_launch(void* const* d_in, const int* in_sizes, int n_in,
                              void* d_out, int out_size, void* d_ws, size_t ws_size,
                              hipStream_t stream) {
    (void)n_in; (void)ws_size; (void)out_size;
    const float* x    = (const float*)d_in[0];
    const float* flin = (const float*)d_in[1];
    const float* fcub = (const float*)d_in[2];
    const float* w    = (const float*)d_in[3];
    const int*   pidx = (const int*)d_in[4];
    float* out = (float*)d_out;

    const int n_lin  = in_sizes[1];
    const int n_cub  = in_sizes[2];
    const int n_tri  = in_sizes[3] / NI;
    const int n_rows = in_sizes[0] / NI;
    const int n_out  = n_lin + n_cub + n_tri;

    // ws layout: meta[n_out] | wpk[WCAP] | tri_start | tri_cnt
    float4* meta      = (float4*)d_ws;
    float*  wpk       = (float*)(meta + n_out);
    int*    tri_start = (int*)(wpk + WCAP);
    int*    tri_cnt   = tri_start + NTRI_MAX;

    if (n_tri > 0)
        logscale_win<<<n_tri, 256, 0, stream>>>(w, NI, tri_start, tri_cnt);
    logscale_pack<<<1, 256, 0, stream>>>(w, flin, fcub, pidx, tri_start, tri_cnt,
                                         meta, wpk, n_lin, n_cub, n_tri);

    const int chunks = (n_out + 255) / 256;
    const int rgs    = (n_rows + R - 1) / R;
    logscale_main<<<rgs * chunks, 256, 0, stream>>>(x, meta, wpk, out,
                                                    n_lin, n_cub, n_out, n_rows,
                                                    chunks);
}

// Round 5
// 296.701 us; speedup vs baseline: 1.2945x; 1.2945x over previous
//
#include <hip/hip_runtime.h>
#include <math.h>

// x: (32,512,2049) fp32 -> out (32,512,1024) fp32
// segments: n_lin (~631) linear, n_cub (~104) cubic, n_tri (~289) tri-max
#define NI 2049
#define R 4               // rows per block/thread
#define WCAP 4096
#define NTRI_MAX 512
#define TBLK 320          // tri-kernel block size (5 waves; n_tri=289 <= 320)
#define XS_SZ 8452        // pad(R*NI-1)+1

// additive pad: +1 float per 32 -> stride-32 gathers fully conflict-free
__device__ __forceinline__ int pad(int i) { return i + (i >> 5); }

// ---------------------------------------------------------------------------
// Pass 1: per tri row, find finite-weight window [start, start+cnt).
// ---------------------------------------------------------------------------
__global__ void logscale_win(const float* __restrict__ w, int n_in,
                             int* __restrict__ tri_start,
                             int* __restrict__ tri_cnt) {
    const int i = blockIdx.x;
    __shared__ int smin, smax;
    if (threadIdx.x == 0) { smin = n_in; smax = -1; }
    __syncthreads();
    int lmin = n_in, lmax = -1;
    const float* wr = w + (size_t)i * n_in;
    for (int b = threadIdx.x; b < n_in; b += blockDim.x) {
        float v = wr[b];
        if (v > -1e30f) { lmin = min(lmin, b); lmax = max(lmax, b); }
    }
    atomicMin(&smin, lmin);
    atomicMax(&smax, lmax);
    __syncthreads();
    if (threadIdx.x == 0) {
        int s = smin, cnt = smax - smin + 1;
        if (cnt < 1) { s = 0; cnt = 1; }
        if (cnt > 64) cnt = 64;          // defensive (real max ~28)
        tri_start[i] = s; tri_cnt[i] = cnt;
    }
}

// ---------------------------------------------------------------------------
// Pass 2 (single block): prefix-sum tri counts, tri meta (start,cnt,off),
// compact-pack tri weights, global min window start.
// ---------------------------------------------------------------------------
__global__ void logscale_pack(const float* __restrict__ w,
                              const int*   __restrict__ tri_start,
                              const int*   __restrict__ tri_cnt,
                              int4*  __restrict__ tmeta,
                              float* __restrict__ wpk,
                              int*   __restrict__ d_lo,
                              int n_tri) {
    __shared__ int offs[NTRI_MAX + 1];
    __shared__ int starts[NTRI_MAX];
    const int tid = threadIdx.x;
    for (int i = tid; i < n_tri; i += blockDim.x) {
        offs[i + 1] = tri_cnt[i];
        starts[i]   = tri_start[i];
    }
    __syncthreads();
    if (tid == 0) {
        offs[0] = 0;
        int mn = starts[0];
        for (int i = 1; i <= n_tri; ++i) {
            offs[i] += offs[i - 1];
            if (i < n_tri) mn = min(mn, starts[i]);
        }
        *d_lo = mn;
    }
    __syncthreads();
    int total = offs[n_tri]; if (total > WCAP) total = WCAP;

    for (int i = tid; i < n_tri; i += blockDim.x) {
        int oa = min(offs[i], WCAP), ob = min(offs[i + 1], WCAP);
        tmeta[i] = make_int4(starts[i], ob - oa, oa, 0);
    }
    for (int p = tid; p < total; p += blockDim.x) {
        int lo = 0, hi = n_tri - 1;
        while (lo < hi) {
            int mid = (lo + hi + 1) >> 1;
            if (offs[mid] <= p) lo = mid; else hi = mid - 1;
        }
        wpk[p] = w[(size_t)lo * NI + starts[lo] + (p - offs[lo])];
    }
}

// ---------------------------------------------------------------------------
// lin+cub: pure streaming, no LDS. Adjacent outputs' indices differ by <=2,
// so gathers are near-coalesced and L1-friendly.
// ---------------------------------------------------------------------------
__global__ __launch_bounds__(256) void logscale_lc(
    const float* __restrict__ x,
    const int*   __restrict__ pidx,
    const float* __restrict__ flin,
    const float* __restrict__ fcub,
    float* __restrict__ out,
    int n_lin, int n_lc, int n_out, int n_rows, int chunks) {

    const int rg = blockIdx.x / chunks;
    const int ch = blockIdx.x - rg * chunks;
    const int o  = ch * 256 + threadIdx.x;
    if (o >= n_lc) return;

    const int row0 = rg * R;
    const int rows = min(R, n_rows - row0);
    const float* xb = x + (size_t)row0 * NI;
    float* ob = out + (size_t)row0 * n_out + o;

    if (o < n_lin) {
        const int i0 = pidx[o];
        const int i1 = pidx[n_lin + o];
        const float f = flin[o];
        for (int r = 0; r < rows; ++r) {
            const float* xr = xb + (size_t)r * NI;
            const float x0 = xr[i0];
            const float x1 = xr[i1];
            __builtin_nontemporal_store(x0 + f * (x1 - x0), ob + (size_t)r * n_out);
        }
    } else {
        const float c = fcub[o - n_lin];
        const int i0 = (int)floorf(c);
        const float f = c - (float)i0;
        for (int r = 0; r < rows; ++r) {
            const float* xr = xb + (size_t)r * NI + i0;
            const float xm1 = xr[-1];
            const float x0  = xr[0];
            const float x1  = xr[1];
            const float x2  = xr[2];
            const float res = x0 + 0.5f * f * (x1 - xm1 +
                    f * (2.0f * xm1 - 5.0f * x0 + 4.0f * x1 - x2 +
                    f * (3.0f * (x0 - x1) + x2 - xm1)));
            __builtin_nontemporal_store(res, ob + (size_t)r * n_out);
        }
    }
}

// ---------------------------------------------------------------------------
// tri: stage the contiguous 4-row span [lo4 .. end of 4th row) via aligned
// float4 global loads into pad-swizzled LDS; weights from global (L1-hot
// 15KB packed table). 33.8KB LDS -> 4 blocks/CU x 5 waves = 62% occ ceiling.
// ---------------------------------------------------------------------------
__global__ __launch_bounds__(TBLK) void logscale_tri(
    const float* __restrict__ x,
    const int4*  __restrict__ tmeta,
    const float* __restrict__ wpk,
    const int*   __restrict__ d_lo,
    float* __restrict__ out,
    int n_lc, int n_out, int n_tri, int n_rows) {

    __shared__ float xs[XS_SZ];
    const int tid  = threadIdx.x;
    const int row0 = blockIdx.x * R;
    const int rows = min(R, n_rows - row0);
    const int lo4  = (*d_lo) & ~3;          // wave-uniform (scalar load)
    const size_t g0 = (size_t)row0 * NI + lo4;  // element idx %4==0 -> 16B aligned
    const int nelem = rows * NI - lo4;

    if (rows == R) {
        const float4* xg = (const float4*)(x + g0);
        const int n4 = nelem >> 2;           // nelem %4 == 0 (R*NI%4==0, lo4%4==0)
        for (int i = tid; i < n4; i += TBLK) {
            const float4 v = xg[i];
            const int b = i << 2;
            xs[pad(b)]     = v.x;
            xs[pad(b + 1)] = v.y;
            xs[pad(b + 2)] = v.z;
            xs[pad(b + 3)] = v.w;
        }
    } else {
        for (int i = tid; i < nelem; i += TBLK) xs[pad(i)] = x[g0 + i];
    }
    __syncthreads();

    for (int o = tid; o < n_tri; o += TBLK) {
        const int4 m = tmeta[o];
        const int s = m.x, cnt = m.y;
        const float* wp = wpk + m.z;
        const int b0 = s - lo4;              // >= 0 by construction of lo
        float* ob = out + (size_t)row0 * n_out + n_lc + o;

        if (rows == R) {
            float a0 = -INFINITY, a1 = -INFINITY, a2 = -INFINITY, a3 = -INFINITY;
            for (int j = 0; j < cnt; ++j) {
                const float wj = wp[j];
                const int l = b0 + j;
                a0 = fmaxf(a0, xs[pad(l)] + wj);
                a1 = fmaxf(a1, xs[pad(l + NI)] + wj);
                a2 = fmaxf(a2, xs[pad(l + 2 * NI)] + wj);
                a3 = fmaxf(a3, xs[pad(l + 3 * NI)] + wj);
            }
            __builtin_nontemporal_store(a0, ob);
            __builtin_nontemporal_store(a1, ob + n_out);
            __builtin_nontemporal_store(a2, ob + 2 * (size_t)n_out);
            __builtin_nontemporal_store(a3, ob + 3 * (size_t)n_out);
        } else {
            for (int r = 0; r < rows; ++r) {
                float mx = -INFINITY;
                const int br = b0 + r * NI;
                for (int j = 0; j < cnt; ++j)
                    mx = fmaxf(mx, xs[pad(br + j)] + wp[j]);
                __builtin_nontemporal_store(mx, ob + (size_t)r * n_out);
            }
        }
    }
}

extern "C" void kernel_launch(void* const* d_in, const int* in_sizes, int n_in,
                              void* d_out, int out_size, void* d_ws, size_t ws_size,
                              hipStream_t stream) {
    (void)n_in; (void)ws_size; (void)out_size;
    const float* x    = (const float*)d_in[0];
    const float* flin = (const float*)d_in[1];
    const float* fcub = (const float*)d_in[2];
    const float* w    = (const float*)d_in[3];
    const int*   pidx = (const int*)d_in[4];
    float* out = (float*)d_out;

    const int n_lin  = in_sizes[1];
    const int n_cub  = in_sizes[2];
    const int n_tri  = in_sizes[3] / NI;
    const int n_rows = in_sizes[0] / NI;
    const int n_out  = n_lin + n_cub + n_tri;
    const int n_lc   = n_lin + n_cub;

    // ws layout: tmeta[NTRI_MAX] int4 | wpk[WCAP] | tri_start | tri_cnt | d_lo
    int4*  tmeta     = (int4*)d_ws;
    float* wpk       = (float*)(tmeta + NTRI_MAX);
    int*   tri_start = (int*)(wpk + WCAP);
    int*   tri_cnt   = tri_start + NTRI_MAX;
    int*   d_lo      = tri_cnt + NTRI_MAX;

    const int rgs = (n_rows + R - 1) / R;

    if (n_tri > 0) {
        logscale_win<<<n_tri, 256, 0, stream>>>(w, NI, tri_start, tri_cnt);
        logscale_pack<<<1, 512, 0, stream>>>(w, tri_start, tri_cnt,
                                             tmeta, wpk, d_lo, n_tri);
    }
    if (n_lc > 0) {
        const int chunks = (n_lc + 255) / 256;
        logscale_lc<<<rgs * chunks, 256, 0, stream>>>(x, pidx, flin, fcub, out,
                                                      n_lin, n_lc, n_out, n_rows,
                                                      chunks);
    }
    if (n_tri > 0) {
        logscale_tri<<<rgs, TBLK, 0, stream>>>(x, tmeta, wpk, d_lo, out,
                                               n_lc, n_out, n_tri, n_rows);
    }
}